// Round 5
// baseline (37.099 us; speedup 1.0000x reference)
//
#include <hip/hip_runtime.h>
#include <math.h>

// B=64, C=1, H=512, W=512 fp32.
// score[b] = cov(x1,x2) / sqrt((v1+eps)*(v2+eps)) per batch plane.
// SINGLE fused kernel, fence-free cross-block reduction:
//   - each of 2048 blocks (32/batch) computes 5 moment partials (fp32 fma,
//     double block-reduce),
//   - quantizes to int64 fixed-point (scale 2^32) and atomicAdds into
//     per-batch u64 accumulators (integer atomics: exact, order-invariant,
//     device-coherent -- no buffer_wbl2 like __threadfence, cf. R3 fail),
//   - inline "s_waitcnt vmcnt(0)" orders value-atomics before the counter
//     atomic; 32nd block per batch reads totals via atomicAdd(p,0) and
//     writes the score in double.
// memset node re-zeros the 2.8 KB accumulator region every call
// (d_ws poisoned 0xAA once; R2 showed a memset node costs ~0 in replay).

#define HW        262144      // 512*512
#define PLANE_F4  65536       // HW/4
#define BPB       32          // blocks per batch plane
#define THREADS   256
#define CHUNK     (PLANE_F4 / BPB)    // 2048 float4 per block per array
#define NBATCH    64
#define EPSN      1e-5
#define QSCALE    4294967296.0        // 2^32
#define QINV      (1.0 / 4294967296.0)

#define ACC(a, c)                                                     \
    s1  += (a.x + a.y) + (a.z + a.w);                                 \
    s2  += (c.x + c.y) + (c.z + c.w);                                 \
    s11 = fmaf(a.x, a.x, s11); s11 = fmaf(a.y, a.y, s11);             \
    s11 = fmaf(a.z, a.z, s11); s11 = fmaf(a.w, a.w, s11);             \
    s22 = fmaf(c.x, c.x, s22); s22 = fmaf(c.y, c.y, s22);             \
    s22 = fmaf(c.z, c.z, s22); s22 = fmaf(c.w, c.w, s22);             \
    s12 = fmaf(a.x, c.x, s12); s12 = fmaf(a.y, c.y, s12);             \
    s12 = fmaf(a.z, c.z, s12); s12 = fmaf(a.w, c.w, s12);

__global__ __launch_bounds__(THREADS, 8) void xcorr_fused(
        const float4* __restrict__ x1, const float4* __restrict__ x2,
        unsigned long long* __restrict__ acc,   // NBATCH*5 u64
        unsigned int* __restrict__ cnt,         // NBATCH u32
        float* __restrict__ out) {
    const int b  = blockIdx.x >> 5;          // / BPB
    const int jb = blockIdx.x & (BPB - 1);
    const int base = jb * CHUNK + threadIdx.x;
    const float4* q1 = x1 + (long long)b * PLANE_F4 + base;
    const float4* q2 = x2 + (long long)b * PLANE_F4 + base;

    float s1 = 0.f, s2 = 0.f, s11 = 0.f, s22 = 0.f, s12 = 0.f;

    {   // batch 0: 8 independent 16B loads issued before any FMA
        const float4 a0 = q1[0 * THREADS];
        const float4 a1 = q1[1 * THREADS];
        const float4 a2 = q1[2 * THREADS];
        const float4 a3 = q1[3 * THREADS];
        const float4 c0 = q2[0 * THREADS];
        const float4 c1 = q2[1 * THREADS];
        const float4 c2 = q2[2 * THREADS];
        const float4 c3 = q2[3 * THREADS];
        ACC(a0, c0) ACC(a1, c1) ACC(a2, c2) ACC(a3, c3)
    }
    {   // batch 1
        const float4 a0 = q1[4 * THREADS];
        const float4 a1 = q1[5 * THREADS];
        const float4 a2 = q1[6 * THREADS];
        const float4 a3 = q1[7 * THREADS];
        const float4 c0 = q2[4 * THREADS];
        const float4 c1 = q2[5 * THREADS];
        const float4 c2 = q2[6 * THREADS];
        const float4 c3 = q2[7 * THREADS];
        ACC(a0, c0) ACC(a1, c1) ACC(a2, c2) ACC(a3, c3)
    }

    // promote to double, wave butterfly then LDS cross-wave (deterministic)
    double d0 = s1, d1 = s2, d2 = s11, d3 = s22, d4 = s12;
    #pragma unroll
    for (int off = 32; off > 0; off >>= 1) {
        d0 += __shfl_down(d0, off, 64);
        d1 += __shfl_down(d1, off, 64);
        d2 += __shfl_down(d2, off, 64);
        d3 += __shfl_down(d3, off, 64);
        d4 += __shfl_down(d4, off, 64);
    }
    __shared__ double lds[4][5];
    const int lane = threadIdx.x & 63;
    const int wv   = threadIdx.x >> 6;
    if (lane == 0) {
        lds[wv][0] = d0; lds[wv][1] = d1; lds[wv][2] = d2;
        lds[wv][3] = d3; lds[wv][4] = d4;
    }
    __syncthreads();

    if (threadIdx.x == 0) {
        const double r0 = (lds[0][0] + lds[1][0]) + (lds[2][0] + lds[3][0]);
        const double r1 = (lds[0][1] + lds[1][1]) + (lds[2][1] + lds[3][1]);
        const double r2 = (lds[0][2] + lds[1][2]) + (lds[2][2] + lds[3][2]);
        const double r3 = (lds[0][3] + lds[1][3]) + (lds[2][3] + lds[3][3]);
        const double r4 = (lds[0][4] + lds[1][4]) + (lds[2][4] + lds[3][4]);

        unsigned long long* a = acc + (long long)b * 5;
        atomicAdd(&a[0], (unsigned long long)(long long)llrint(r0 * QSCALE));
        atomicAdd(&a[1], (unsigned long long)(long long)llrint(r1 * QSCALE));
        atomicAdd(&a[2], (unsigned long long)(long long)llrint(r2 * QSCALE));
        atomicAdd(&a[3], (unsigned long long)(long long)llrint(r3 * QSCALE));
        atomicAdd(&a[4], (unsigned long long)(long long)llrint(r4 * QSCALE));
        // order value-atomics before the counter atomic (this wave only --
        // NOT an L2 writeback like __threadfence)
        asm volatile("s_waitcnt vmcnt(0)" ::: "memory");
        const unsigned int old = atomicAdd(&cnt[b], 1u);
        if (old == BPB - 1) {
            // coherent read-back of the completed totals
            const double t0 = (double)(long long)atomicAdd(&a[0], 0ULL) * QINV;
            const double t1 = (double)(long long)atomicAdd(&a[1], 0ULL) * QINV;
            const double t2 = (double)(long long)atomicAdd(&a[2], 0ULL) * QINV;
            const double t3 = (double)(long long)atomicAdd(&a[3], 0ULL) * QINV;
            const double t4 = (double)(long long)atomicAdd(&a[4], 0ULL) * QINV;
            const double N  = (double)HW;
            const double m1 = t0 / N, m2 = t1 / N;
            const double v1 = t2 / N - m1 * m1;
            const double v2 = t3 / N - m2 * m2;
            const double cv = t4 / N - m1 * m2;
            out[b] = (float)(cv / sqrt((v1 + EPSN) * (v2 + EPSN)));
        }
    }
}

extern "C" void kernel_launch(void* const* d_in, const int* in_sizes, int n_in,
                              void* d_out, int out_size, void* d_ws, size_t ws_size,
                              hipStream_t stream) {
    const float4* x1 = (const float4*)d_in[0];
    const float4* x2 = (const float4*)d_in[1];
    unsigned long long* acc = (unsigned long long*)d_ws;           // 64*5*8 = 2560 B
    unsigned int* cnt = (unsigned int*)((char*)d_ws + NBATCH * 5 * sizeof(unsigned long long));
    float* out = (float*)d_out;

    // zero accumulators + counters (2816 B) every call: deterministic,
    // required because d_ws is poisoned once and never re-poisoned.
    hipMemsetAsync(d_ws, 0, NBATCH * 5 * sizeof(unsigned long long)
                            + NBATCH * sizeof(unsigned int), stream);
    xcorr_fused<<<NBATCH * BPB, THREADS, 0, stream>>>(x1, x2, acc, cnt, out);
}

// Round 6
// 27.434 us; speedup vs baseline: 1.3523x; 1.3523x over previous
//
#include <hip/hip_runtime.h>
#include <math.h>

// B=64, C=1, H=512, W=512 fp32.
// score[b] = cov(x1,x2) / sqrt((v1+eps)*(v2+eps)) per batch plane.
// Two kernels (fusion disproven twice: R3 __threadfence = serialized
// buffer_wbl2, +73us; R5 int64-atomic tree = +9us).
// Stage 1: 2048 blocks x 256 thr, contiguous 32KB windows, fp32 fma,
//          double tree reduce -> 5 partials/block stored SoA.
// Stage 2: 64 blocks x 64 thr (one per batch): coalesced partial loads,
//          5-level fixed shuffle tree, lane 0 finalizes in double.

#define HW        262144      // 512*512
#define PLANE_F4  65536       // HW/4
#define BPB       32          // blocks per batch plane
#define THREADS   256
#define CHUNK     (PLANE_F4 / BPB)    // 2048 float4 per block per array
#define NBLOCKS   (64 * BPB)          // 2048
#define NBATCH    64
#define EPSN      1e-5

#define ACC(a, c)                                                     \
    s1  += (a.x + a.y) + (a.z + a.w);                                 \
    s2  += (c.x + c.y) + (c.z + c.w);                                 \
    s11 = fmaf(a.x, a.x, s11); s11 = fmaf(a.y, a.y, s11);             \
    s11 = fmaf(a.z, a.z, s11); s11 = fmaf(a.w, a.w, s11);             \
    s22 = fmaf(c.x, c.x, s22); s22 = fmaf(c.y, c.y, s22);             \
    s22 = fmaf(c.z, c.z, s22); s22 = fmaf(c.w, c.w, s22);             \
    s12 = fmaf(a.x, c.x, s12); s12 = fmaf(a.y, c.y, s12);             \
    s12 = fmaf(a.z, c.z, s12); s12 = fmaf(a.w, c.w, s12);

__global__ __launch_bounds__(THREADS, 8) void xcorr_partial(
        const float4* __restrict__ x1, const float4* __restrict__ x2,
        double* __restrict__ part) {
    const int b  = blockIdx.x >> 5;          // / BPB
    const int jb = blockIdx.x & (BPB - 1);
    const int base = jb * CHUNK + threadIdx.x;
    const float4* q1 = x1 + (long long)b * PLANE_F4 + base;
    const float4* q2 = x2 + (long long)b * PLANE_F4 + base;

    float s1 = 0.f, s2 = 0.f, s11 = 0.f, s22 = 0.f, s12 = 0.f;

    {   // batch 0: 8 independent 16B loads issued before any FMA
        const float4 a0 = q1[0 * THREADS];
        const float4 a1 = q1[1 * THREADS];
        const float4 a2 = q1[2 * THREADS];
        const float4 a3 = q1[3 * THREADS];
        const float4 c0 = q2[0 * THREADS];
        const float4 c1 = q2[1 * THREADS];
        const float4 c2 = q2[2 * THREADS];
        const float4 c3 = q2[3 * THREADS];
        ACC(a0, c0) ACC(a1, c1) ACC(a2, c2) ACC(a3, c3)
    }
    {   // batch 1
        const float4 a0 = q1[4 * THREADS];
        const float4 a1 = q1[5 * THREADS];
        const float4 a2 = q1[6 * THREADS];
        const float4 a3 = q1[7 * THREADS];
        const float4 c0 = q2[4 * THREADS];
        const float4 c1 = q2[5 * THREADS];
        const float4 c2 = q2[6 * THREADS];
        const float4 c3 = q2[7 * THREADS];
        ACC(a0, c0) ACC(a1, c1) ACC(a2, c2) ACC(a3, c3)
    }

    // promote to double, wave butterfly then LDS cross-wave (deterministic)
    double d0 = s1, d1 = s2, d2 = s11, d3 = s22, d4 = s12;
    #pragma unroll
    for (int off = 32; off > 0; off >>= 1) {
        d0 += __shfl_down(d0, off, 64);
        d1 += __shfl_down(d1, off, 64);
        d2 += __shfl_down(d2, off, 64);
        d3 += __shfl_down(d3, off, 64);
        d4 += __shfl_down(d4, off, 64);
    }
    __shared__ double lds[4][5];
    const int lane = threadIdx.x & 63;
    const int wv   = threadIdx.x >> 6;
    if (lane == 0) {
        lds[wv][0] = d0; lds[wv][1] = d1; lds[wv][2] = d2;
        lds[wv][3] = d3; lds[wv][4] = d4;
    }
    __syncthreads();
    if (threadIdx.x == 0) {
        // SoA: part[i*NBLOCKS + bid] -> stage-2 loads coalesce
        #pragma unroll
        for (int i = 0; i < 5; ++i)
            part[i * NBLOCKS + blockIdx.x] =
                (lds[0][i] + lds[1][i]) + (lds[2][i] + lds[3][i]);
    }
}

__global__ __launch_bounds__(64) void xcorr_final(
        const double* __restrict__ part, float* __restrict__ out) {
    const int b = blockIdx.x;             // one block per batch
    const int j = threadIdx.x;            // lanes 0..63 (32 carry data)
    const int idx = b * BPB + (j & 31);   // partial index for this batch
    double t0 = 0, t1 = 0, t2 = 0, t3 = 0, t4 = 0;
    if (j < 32) {
        t0 = part[0 * NBLOCKS + idx];
        t1 = part[1 * NBLOCKS + idx];
        t2 = part[2 * NBLOCKS + idx];
        t3 = part[3 * NBLOCKS + idx];
        t4 = part[4 * NBLOCKS + idx];
    }
    #pragma unroll
    for (int off = 16; off > 0; off >>= 1) {   // fixed tree: deterministic
        t0 += __shfl_down(t0, off, 64);
        t1 += __shfl_down(t1, off, 64);
        t2 += __shfl_down(t2, off, 64);
        t3 += __shfl_down(t3, off, 64);
        t4 += __shfl_down(t4, off, 64);
    }
    if (j == 0) {
        const double N  = (double)HW;
        const double m1 = t0 / N, m2 = t1 / N;
        const double v1 = t2 / N - m1 * m1;
        const double v2 = t3 / N - m2 * m2;
        const double cv = t4 / N - m1 * m2;
        out[b] = (float)(cv / sqrt((v1 + EPSN) * (v2 + EPSN)));
    }
}

extern "C" void kernel_launch(void* const* d_in, const int* in_sizes, int n_in,
                              void* d_out, int out_size, void* d_ws, size_t ws_size,
                              hipStream_t stream) {
    const float4* x1 = (const float4*)d_in[0];
    const float4* x2 = (const float4*)d_in[1];
    double* part = (double*)d_ws;          // 5*2048 doubles = 80 KiB, SoA
    float* out = (float*)d_out;

    xcorr_partial<<<NBLOCKS, THREADS, 0, stream>>>(x1, x2, part);
    xcorr_final<<<NBATCH, 64, 0, stream>>>(part, out);
}

// Round 7
// 27.379 us; speedup vs baseline: 1.3550x; 1.0020x over previous
//
#include <hip/hip_runtime.h>
#include <math.h>

// B=64, C=1, H=512, W=512 fp32.
// score[b] = cov(x1,x2) / sqrt((v1+eps)*(v2+eps)) per batch plane.
// Two kernels (fusion disproven: R3 __threadfence=serialized buffer_wbl2;
// R5 int64-atomic tree both regressed).
// R7 change: halve wave count -- 1024 blocks x 256 thr, 16 float4 per
// thread per array (2x work/wave, half the f64-shuffle tail and half the
// dispatches); __launch_bounds__(256,4) so the allocator can hold 8-deep
// load batches (R2's (256,8) capped VGPR=32 and serialized loads).
// Stage 2: 64 blocks x 64 thr, 16 partials/batch, fixed shuffle tree.

#define HW        262144      // 512*512
#define PLANE_F4  65536       // HW/4
#define BPB       16          // blocks per batch plane
#define THREADS   256
#define CHUNK     (PLANE_F4 / BPB)    // 4096 float4 per block per array
#define NBLOCKS   (64 * BPB)          // 1024
#define NBATCH    64
#define EPSN      1e-5

#define ACC(a, c)                                                     \
    s1  += (a.x + a.y) + (a.z + a.w);                                 \
    s2  += (c.x + c.y) + (c.z + c.w);                                 \
    s11 = fmaf(a.x, a.x, s11); s11 = fmaf(a.y, a.y, s11);             \
    s11 = fmaf(a.z, a.z, s11); s11 = fmaf(a.w, a.w, s11);             \
    s22 = fmaf(c.x, c.x, s22); s22 = fmaf(c.y, c.y, s22);             \
    s22 = fmaf(c.z, c.z, s22); s22 = fmaf(c.w, c.w, s22);             \
    s12 = fmaf(a.x, c.x, s12); s12 = fmaf(a.y, c.y, s12);             \
    s12 = fmaf(a.z, c.z, s12); s12 = fmaf(a.w, c.w, s12);

// one batch = 8 independent 16B loads (4 per array) issued before any FMA
#define BATCH8(k)                                                     \
    {                                                                 \
        const float4 a0 = q1[(4*(k)+0) * THREADS];                    \
        const float4 a1 = q1[(4*(k)+1) * THREADS];                    \
        const float4 a2 = q1[(4*(k)+2) * THREADS];                    \
        const float4 a3 = q1[(4*(k)+3) * THREADS];                    \
        const float4 c0 = q2[(4*(k)+0) * THREADS];                    \
        const float4 c1 = q2[(4*(k)+1) * THREADS];                    \
        const float4 c2 = q2[(4*(k)+2) * THREADS];                    \
        const float4 c3 = q2[(4*(k)+3) * THREADS];                    \
        ACC(a0, c0) ACC(a1, c1) ACC(a2, c2) ACC(a3, c3)               \
    }

__global__ __launch_bounds__(THREADS, 4) void xcorr_partial(
        const float4* __restrict__ x1, const float4* __restrict__ x2,
        double* __restrict__ part) {
    const int b  = blockIdx.x >> 4;          // / BPB
    const int jb = blockIdx.x & (BPB - 1);
    const int base = jb * CHUNK + threadIdx.x;
    const float4* q1 = x1 + (long long)b * PLANE_F4 + base;
    const float4* q2 = x2 + (long long)b * PLANE_F4 + base;

    float s1 = 0.f, s2 = 0.f, s11 = 0.f, s22 = 0.f, s12 = 0.f;

    BATCH8(0) BATCH8(1) BATCH8(2) BATCH8(3)   // 16 f4 per array per thread

    // promote to double, wave butterfly then LDS cross-wave (deterministic)
    double d0 = s1, d1 = s2, d2 = s11, d3 = s22, d4 = s12;
    #pragma unroll
    for (int off = 32; off > 0; off >>= 1) {
        d0 += __shfl_down(d0, off, 64);
        d1 += __shfl_down(d1, off, 64);
        d2 += __shfl_down(d2, off, 64);
        d3 += __shfl_down(d3, off, 64);
        d4 += __shfl_down(d4, off, 64);
    }
    __shared__ double lds[4][5];
    const int lane = threadIdx.x & 63;
    const int wv   = threadIdx.x >> 6;
    if (lane == 0) {
        lds[wv][0] = d0; lds[wv][1] = d1; lds[wv][2] = d2;
        lds[wv][3] = d3; lds[wv][4] = d4;
    }
    __syncthreads();
    if (threadIdx.x == 0) {
        // SoA: part[i*NBLOCKS + bid] -> stage-2 loads coalesce
        #pragma unroll
        for (int i = 0; i < 5; ++i)
            part[i * NBLOCKS + blockIdx.x] =
                (lds[0][i] + lds[1][i]) + (lds[2][i] + lds[3][i]);
    }
}

__global__ __launch_bounds__(64) void xcorr_final(
        const double* __restrict__ part, float* __restrict__ out) {
    const int b = blockIdx.x;             // one block per batch
    const int j = threadIdx.x;            // lanes 0..63 (16 carry data)
    const int idx = b * BPB + (j & 15);   // partial index for this batch
    double t0 = 0, t1 = 0, t2 = 0, t3 = 0, t4 = 0;
    if (j < 16) {
        t0 = part[0 * NBLOCKS + idx];
        t1 = part[1 * NBLOCKS + idx];
        t2 = part[2 * NBLOCKS + idx];
        t3 = part[3 * NBLOCKS + idx];
        t4 = part[4 * NBLOCKS + idx];
    }
    #pragma unroll
    for (int off = 8; off > 0; off >>= 1) {    // fixed tree: deterministic
        t0 += __shfl_down(t0, off, 64);
        t1 += __shfl_down(t1, off, 64);
        t2 += __shfl_down(t2, off, 64);
        t3 += __shfl_down(t3, off, 64);
        t4 += __shfl_down(t4, off, 64);
    }
    if (j == 0) {
        const double N  = (double)HW;
        const double m1 = t0 / N, m2 = t1 / N;
        const double v1 = t2 / N - m1 * m1;
        const double v2 = t3 / N - m2 * m2;
        const double cv = t4 / N - m1 * m2;
        out[b] = (float)(cv / sqrt((v1 + EPSN) * (v2 + EPSN)));
    }
}

extern "C" void kernel_launch(void* const* d_in, const int* in_sizes, int n_in,
                              void* d_out, int out_size, void* d_ws, size_t ws_size,
                              hipStream_t stream) {
    const float4* x1 = (const float4*)d_in[0];
    const float4* x2 = (const float4*)d_in[1];
    double* part = (double*)d_ws;          // 5*1024 doubles = 40 KiB, SoA
    float* out = (float*)d_out;

    xcorr_partial<<<NBLOCKS, THREADS, 0, stream>>>(x1, x2, part);
    xcorr_final<<<NBATCH, 64, 0, stream>>>(part, out);
}